// Round 1
// baseline (83.077 us; speedup 1.0000x reference)
//
#include <hip/hip_runtime.h>
#include <math.h>

// Problem constants (fixed by setup_inputs)
#define BB 4
#define NI 64
#define CC 64
#define HH 256
#define WW 256

// numpy/jax "reflect" (mirror, edge not repeated), pad=1 so i in [-1, n]
__device__ __forceinline__ int refl(int i, int n) {
    i = (i < 0) ? -i : i;
    return (i >= n) ? (2 * n - 2 - i) : i;
}

// One thread per (b, h, w) pixel.
// Phase 1: 9-tap conv over 64 channels (+bias), softmax -> ff[9] in registers.
// Phase 2: loop 64 channels of inpt, apply ff to the reflected 3x3 window.
__global__ __launch_bounds__(256) void pff_fused(
    const float* __restrict__ features,
    const float* __restrict__ inpt,
    const float* __restrict__ wgt,
    const float* __restrict__ bias,
    float* __restrict__ out)
{
    const int tid = threadIdx.x;
    const int wx = blockIdx.x * 64 + (tid & 63);   // W: 4 strips of 64
    const int hy = blockIdx.y * 4 + (tid >> 6);    // H: 64 groups of 4
    const int b  = blockIdx.z;

    const int ih0 = refl(hy - 1, HH);
    const int ih1 = hy;
    const int ih2 = refl(hy + 1, HH);
    const int iw0 = refl(wx - 1, WW);
    const int iw1 = wx;
    const int iw2 = refl(wx + 1, WW);

    const int r0 = ih0 * WW, r1 = ih1 * WW, r2 = ih2 * WW;

    float acc[9];
    #pragma unroll
    for (int k = 0; k < 9; ++k) acc[k] = bias[k];

    // ---- Phase 1: conv over NI channels ----
    const float* fb = features + (size_t)b * NI * HH * WW;
    for (int ni = 0; ni < NI; ++ni) {
        const float* fc = fb + (size_t)ni * HH * WW;
        float f[9];
        f[0] = fc[r0 + iw0]; f[1] = fc[r0 + iw1]; f[2] = fc[r0 + iw2];
        f[3] = fc[r1 + iw0]; f[4] = fc[r1 + iw1]; f[5] = fc[r1 + iw2];
        f[6] = fc[r2 + iw0]; f[7] = fc[r2 + iw1]; f[8] = fc[r2 + iw2];

        // wgt layout: [9][NI][3][3]; index wave-uniform -> scalar loads
        const float* wn = wgt + ni * 9;
        #pragma unroll
        for (int k = 0; k < 9; ++k) {
            const float* wk = wn + k * (NI * 9);
            #pragma unroll
            for (int t = 0; t < 9; ++t)
                acc[k] = fmaf(f[t], wk[t], acc[k]);
        }
    }

    // ---- softmax over the 9 taps ----
    float m = acc[0];
    #pragma unroll
    for (int k = 1; k < 9; ++k) m = fmaxf(m, acc[k]);
    float s = 0.f;
    #pragma unroll
    for (int k = 0; k < 9; ++k) { acc[k] = __expf(acc[k] - m); s += acc[k]; }
    const float inv = 1.f / s;
    #pragma unroll
    for (int k = 0; k < 9; ++k) acc[k] *= inv;

    // ---- Phase 2: apply per-pixel filter to all channels of inpt ----
    const float* ib = inpt + (size_t)b * CC * HH * WW;
    float* ob = out + (size_t)b * CC * HH * WW;
    const size_t opix = (size_t)hy * WW + wx;
    for (int c = 0; c < CC; ++c) {
        const float* ic = ib + (size_t)c * HH * WW;
        float o = acc[0] * ic[r0 + iw0];
        o = fmaf(acc[1], ic[r0 + iw1], o);
        o = fmaf(acc[2], ic[r0 + iw2], o);
        o = fmaf(acc[3], ic[r1 + iw0], o);
        o = fmaf(acc[4], ic[r1 + iw1], o);
        o = fmaf(acc[5], ic[r1 + iw2], o);
        o = fmaf(acc[6], ic[r2 + iw0], o);
        o = fmaf(acc[7], ic[r2 + iw1], o);
        o = fmaf(acc[8], ic[r2 + iw2], o);
        ob[(size_t)c * HH * WW + opix] = o;
    }
}

extern "C" void kernel_launch(void* const* d_in, const int* in_sizes, int n_in,
                              void* d_out, int out_size, void* d_ws, size_t ws_size,
                              hipStream_t stream) {
    const float* features = (const float*)d_in[0];
    const float* inpt     = (const float*)d_in[1];
    const float* wgt      = (const float*)d_in[2];
    const float* bias     = (const float*)d_in[3];
    float* out            = (float*)d_out;

    dim3 grid(WW / 64, HH / 4, BB);  // (4, 64, 4) = 1024 blocks
    dim3 block(256);
    pff_fused<<<grid, block, 0, stream>>>(features, inpt, wgt, bias, out);
}